// Round 1
// baseline (262.999 us; speedup 1.0000x reference)
//
#include <hip/hip_runtime.h>
#include <cstdint>

#define NXC 768
#define NHEAD 12
#define DH 64
#define BB 2
#define SS 2048
#define MTOT (BB*SS)        // 4096
#define NQKV (3*NXC)        // 2304
#define PRESENT_HALF (BB*NHEAD*SS*DH)   // 3145728

typedef __bf16 bf16x8 __attribute__((ext_vector_type(8)));
typedef float f32x4 __attribute__((ext_vector_type(4)));

__device__ __forceinline__ uint16_t f2bf(float f) {
    uint32_t u = __builtin_bit_cast(uint32_t, f);
    uint32_t r = (u + 0x7FFFu + ((u >> 16) & 1u)) >> 16;
    return (uint16_t)r;
}

// ---------------- prep kernels ----------------

__global__ void prep_x(const float* __restrict__ in, uint16_t* __restrict__ out) {
    int i = blockIdx.x * 256 + threadIdx.x;   // over n/4 = 786432
    float4 v = ((const float4*)in)[i];
    ushort4 o;
    o.x = f2bf(v.x); o.y = f2bf(v.y); o.z = f2bf(v.z); o.w = f2bf(v.w);
    ((ushort4*)out)[i] = o;
}

// W_effT[n][k] = w_attn[k][n] + 16 * sum_r lora_A[(c*8+r)*768+k] * lora_B[n*8+r]
__global__ void prep_weff(const float* __restrict__ w_attn,
                          const float* __restrict__ lora_A,
                          const float* __restrict__ lora_B,
                          uint16_t* __restrict__ weffT) {
    int i = blockIdx.x * 256 + threadIdx.x;   // over 2304*768
    int n = i / NXC, k = i - n * NXC;
    int c = n / NXC;
    float acc = w_attn[(size_t)k * NQKV + n];
    float d = 0.f;
#pragma unroll
    for (int r = 0; r < 8; ++r)
        d += lora_A[(size_t)(c * 8 + r) * NXC + k] * lora_B[(size_t)n * 8 + r];
    weffT[(size_t)n * NXC + k] = f2bf(acc + 16.0f * d);
}

__global__ void prep_wproj(const float* __restrict__ w_proj, uint16_t* __restrict__ wpT) {
    int i = blockIdx.x * 256 + threadIdx.x;   // over 768*768
    int n = i / NXC, k = i - n * NXC;
    wpT[(size_t)n * NXC + k] = f2bf(w_proj[(size_t)k * NXC + n]);
}

// ---------------- GEMM: C = A[M,768] * BT[N,768]^T ----------------
// MODE 0: qkv epilogue (scatter to q/k/v + present), MODE 1: plain + bias to outf

template<int MODE>
__global__ __launch_bounds__(256) void gemm_bt(
    const uint16_t* __restrict__ Abf, const uint16_t* __restrict__ BTbf,
    const float* __restrict__ bias, float* __restrict__ outf,
    uint16_t* __restrict__ q_bf, uint16_t* __restrict__ k_bf,
    uint16_t* __restrict__ vT_bf) {
    __shared__ uint16_t As[128][48];
    __shared__ uint16_t Bs[128][48];
    const int t = threadIdx.x;
    const int lane = t & 63;
    const int w = t >> 6;
    const int wr = (w >> 1) * 64;
    const int wc = (w & 1) * 64;
    const int rr = t >> 2;
    const int cc = (t & 3) << 3;
    const size_t arow0 = (size_t)blockIdx.y * 128;
    const size_t brow0 = (size_t)blockIdx.x * 128;
    const uint16_t* Ap = Abf + (arow0 + rr) * NXC + cc;
    const uint16_t* Bp = BTbf + (brow0 + rr) * NXC + cc;
    const int lr16 = lane & 15;
    const int lk = (lane >> 4) << 3;

    f32x4 acc[4][4];
#pragma unroll
    for (int m = 0; m < 4; ++m)
#pragma unroll
        for (int n = 0; n < 4; ++n) acc[m][n] = (f32x4){0.f, 0.f, 0.f, 0.f};

    for (int kt = 0; kt < 24; ++kt) {
        const int k0 = kt << 5;
        uint4 a0 = *(const uint4*)(Ap + k0);
        uint4 a1 = *(const uint4*)(Ap + (size_t)64 * NXC + k0);
        uint4 b0 = *(const uint4*)(Bp + k0);
        uint4 b1 = *(const uint4*)(Bp + (size_t)64 * NXC + k0);
        __syncthreads();
        *(uint4*)&As[rr][cc] = a0;
        *(uint4*)&As[rr + 64][cc] = a1;
        *(uint4*)&Bs[rr][cc] = b0;
        *(uint4*)&Bs[rr + 64][cc] = b1;
        __syncthreads();
        bf16x8 af[4], bv[4];
#pragma unroll
        for (int m = 0; m < 4; ++m) af[m] = *(const bf16x8*)&As[wr + m * 16 + lr16][lk];
#pragma unroll
        for (int n = 0; n < 4; ++n) bv[n] = *(const bf16x8*)&Bs[wc + n * 16 + lr16][lk];
#pragma unroll
        for (int m = 0; m < 4; ++m)
#pragma unroll
            for (int n = 0; n < 4; ++n)
                acc[m][n] = __builtin_amdgcn_mfma_f32_16x16x32_bf16(af[m], bv[n], acc[m][n], 0, 0, 0);
    }

    const int rowb = (lane >> 4) << 2;
#pragma unroll
    for (int m = 0; m < 4; ++m) {
        int grow0 = (int)arow0 + wr + m * 16 + rowb;
#pragma unroll
        for (int n = 0; n < 4; ++n) {
            int gcol = (int)brow0 + wc + n * 16 + lr16;
            float bvs = bias[gcol];
            if (MODE == 1) {
#pragma unroll
                for (int ri = 0; ri < 4; ++ri) {
                    int grow = grow0 + ri;
                    outf[(size_t)grow * NXC + gcol] = acc[m][n][ri] + bvs;
                }
            } else {
                int c = gcol >= 2 * NXC ? 2 : (gcol >= NXC ? 1 : 0);
                int e = gcol - c * NXC;
                int h = e >> 6, d = e & 63;
#pragma unroll
                for (int ri = 0; ri < 4; ++ri) {
                    int grow = grow0 + ri;
                    int b = grow >> 11, s = grow & 2047;
                    float v = acc[m][n][ri] + bvs;
                    size_t hidx = ((size_t)(b * NHEAD + h) * SS + s);
                    if (c == 0) {
                        q_bf[hidx * 64 + d] = f2bf(v);
                    } else if (c == 1) {
                        k_bf[hidx * 64 + d] = f2bf(v);
                        outf[hidx * 64 + d] = v;
                    } else {
                        vT_bf[((size_t)(b * NHEAD + h) * 64 + d) * SS + s] = f2bf(v);
                        outf[PRESENT_HALF + hidx * 64 + d] = v;
                    }
                }
            }
        }
    }
}

// ---------------- flash attention ----------------
// grid (S/64, B*H); block 256 (4 waves); wave w handles 16 q-rows

__global__ __launch_bounds__(256) void attn_kernel(
    const uint16_t* __restrict__ qb, const uint16_t* __restrict__ kb,
    const uint16_t* __restrict__ vtb, uint16_t* __restrict__ ab) {
    __shared__ uint16_t Pl[4][16][48];
    const int t = threadIdx.x;
    const int w = t >> 6, lane = t & 63;
    const int lr = lane & 15, lg = lane >> 4;
    const int bh = blockIdx.y;
    const uint16_t* qh = qb + (size_t)bh * (SS * 64);
    const uint16_t* kh = kb + (size_t)bh * (SS * 64);
    const uint16_t* vh = vtb + (size_t)bh * (64 * SS);
    const int qbase = blockIdx.x * 64 + w * 16;

    bf16x8 qf0 = *(const bf16x8*)(qh + (size_t)(qbase + lr) * 64 + lg * 8);
    bf16x8 qf1 = *(const bf16x8*)(qh + (size_t)(qbase + lr) * 64 + 32 + lg * 8);

    f32x4 o[4];
    float m_run[4], l_run[4];
#pragma unroll
    for (int i = 0; i < 4; ++i) { o[i] = (f32x4){0.f,0.f,0.f,0.f}; m_run[i] = -3.0e38f; l_run[i] = 0.f; }

    const int nkt = (qbase + 47) >> 5;
    const float LOG2E = 1.44269504f;

    for (int kt = 0; kt < nkt; ++kt) {
        const int kbase = kt << 5;
        f32x4 s0 = (f32x4){0.f,0.f,0.f,0.f}, s1 = (f32x4){0.f,0.f,0.f,0.f};
        {
            const uint16_t* kp0 = kh + (size_t)(kbase + lr) * 64 + lg * 8;
            const uint16_t* kp1 = kh + (size_t)(kbase + 16 + lr) * 64 + lg * 8;
            bf16x8 k00 = *(const bf16x8*)(kp0);
            bf16x8 k01 = *(const bf16x8*)(kp0 + 32);
            bf16x8 k10 = *(const bf16x8*)(kp1);
            bf16x8 k11 = *(const bf16x8*)(kp1 + 32);
            s0 = __builtin_amdgcn_mfma_f32_16x16x32_bf16(qf0, k00, s0, 0, 0, 0);
            s0 = __builtin_amdgcn_mfma_f32_16x16x32_bf16(qf1, k01, s0, 0, 0, 0);
            s1 = __builtin_amdgcn_mfma_f32_16x16x32_bf16(qf0, k10, s1, 0, 0, 0);
            s1 = __builtin_amdgcn_mfma_f32_16x16x32_bf16(qf1, k11, s1, 0, 0, 0);
        }
        const bool domask = (kbase + 31 > qbase);
        float tmax[4];
#pragma unroll
        for (int ri = 0; ri < 4; ++ri) {
            int row = qbase + lg * 4 + ri;
            float a0 = s0[ri] * 0.125f, a1 = s1[ri] * 0.125f;
            if (domask) {
                if (kbase + lr > row) a0 = -3.0e38f;
                if (kbase + 16 + lr > row) a1 = -3.0e38f;
            }
            s0[ri] = a0; s1[ri] = a1;
            tmax[ri] = fmaxf(a0, a1);
        }
#pragma unroll
        for (int d = 1; d < 16; d <<= 1)
#pragma unroll
            for (int ri = 0; ri < 4; ++ri)
                tmax[ri] = fmaxf(tmax[ri], __shfl_xor(tmax[ri], d));
        float corr[4], psum[4];
#pragma unroll
        for (int ri = 0; ri < 4; ++ri) {
            float nm = fmaxf(m_run[ri], tmax[ri]);
            corr[ri] = __builtin_amdgcn_exp2f((m_run[ri] - nm) * LOG2E);
            float p0 = __builtin_amdgcn_exp2f((s0[ri] - nm) * LOG2E);
            float p1 = __builtin_amdgcn_exp2f((s1[ri] - nm) * LOG2E);
            s0[ri] = p0; s1[ri] = p1;
            psum[ri] = p0 + p1;
            m_run[ri] = nm;
        }
#pragma unroll
        for (int d = 1; d < 16; d <<= 1)
#pragma unroll
            for (int ri = 0; ri < 4; ++ri)
                psum[ri] += __shfl_xor(psum[ri], d);
#pragma unroll
        for (int ri = 0; ri < 4; ++ri) l_run[ri] = l_run[ri] * corr[ri] + psum[ri];
#pragma unroll
        for (int nb = 0; nb < 4; ++nb)
#pragma unroll
            for (int ri = 0; ri < 4; ++ri) o[nb][ri] *= corr[ri];
#pragma unroll
        for (int ri = 0; ri < 4; ++ri) {
            Pl[w][lg * 4 + ri][lr] = f2bf(s0[ri]);
            Pl[w][lg * 4 + ri][16 + lr] = f2bf(s1[ri]);
        }
        asm volatile("s_waitcnt lgkmcnt(0)" ::: "memory");
        __builtin_amdgcn_sched_barrier(0);
        bf16x8 pa = *(const bf16x8*)&Pl[w][lr][lg * 8];
#pragma unroll
        for (int nb = 0; nb < 4; ++nb) {
            bf16x8 vf = *(const bf16x8*)(vh + (size_t)(nb * 16 + lr) * SS + kbase + lg * 8);
            o[nb] = __builtin_amdgcn_mfma_f32_16x16x32_bf16(pa, vf, o[nb], 0, 0, 0);
        }
    }

    const int b = bh / NHEAD, h = bh - b * NHEAD;
    uint16_t* abp = ab + ((size_t)b * SS) * NXC + (size_t)h * 64;
#pragma unroll
    for (int nb = 0; nb < 4; ++nb)
#pragma unroll
        for (int ri = 0; ri < 4; ++ri) {
            int row = qbase + lg * 4 + ri;
            abp[(size_t)row * NXC + nb * 16 + lr] = f2bf(o[nb][ri] / l_run[ri]);
        }
}

// ---------------- launch ----------------

extern "C" void kernel_launch(void* const* d_in, const int* in_sizes, int n_in,
                              void* d_out, int out_size, void* d_ws, size_t ws_size,
                              hipStream_t stream) {
    const float* x      = (const float*)d_in[0];
    const float* w_attn = (const float*)d_in[1];
    const float* b_attn = (const float*)d_in[2];
    const float* lora_A = (const float*)d_in[3];
    const float* lora_B = (const float*)d_in[4];
    const float* w_proj = (const float*)d_in[5];
    const float* b_proj = (const float*)d_in[6];
    float* out = (float*)d_out;
    float* present = out + (size_t)MTOT * NXC;   // 3145728

    uint16_t* ws    = (uint16_t*)d_ws;
    uint16_t* x_bf  = ws;                         // 3145728
    uint16_t* weffT = x_bf + 3145728;             // 1769472
    uint16_t* wpT   = weffT + 1769472;            // 589824
    uint16_t* q_bf  = wpT + 589824;               // 3145728
    uint16_t* k_bf  = q_bf + 3145728;             // 3145728
    uint16_t* vT_bf = k_bf + 3145728;             // 3145728
    uint16_t* a_bf  = vT_bf + 3145728;            // 3145728

    prep_x<<<dim3(3072), dim3(256), 0, stream>>>(x, x_bf);
    prep_weff<<<dim3(6912), dim3(256), 0, stream>>>(w_attn, lora_A, lora_B, weffT);
    prep_wproj<<<dim3(2304), dim3(256), 0, stream>>>(w_proj, wpT);

    gemm_bt<0><<<dim3(18, 32), dim3(256), 0, stream>>>(x_bf, weffT, b_attn, present,
                                                       q_bf, k_bf, vT_bf);
    attn_kernel<<<dim3(SS / 64, BB * NHEAD), dim3(256), 0, stream>>>(q_bf, k_bf, vT_bf, a_bf);
    gemm_bt<1><<<dim3(6, 32), dim3(256), 0, stream>>>(a_bf, wpT, b_proj, out,
                                                      nullptr, nullptr, nullptr);
}

// Round 2
// 166.017 us; speedup vs baseline: 1.5842x; 1.5842x over previous
//
#include <hip/hip_runtime.h>
#include <cstdint>

#define NXC 768
#define NHEAD 12
#define DH 64
#define BB 2
#define SS 2048
#define MTOT (BB*SS)        // 4096
#define NQKV (3*NXC)        // 2304
#define PRESENT_HALF (BB*NHEAD*SS*DH)   // 3145728

typedef __bf16 bf16x8 __attribute__((ext_vector_type(8)));
typedef float f32x4 __attribute__((ext_vector_type(4)));
typedef float f32x16 __attribute__((ext_vector_type(16)));

__device__ __forceinline__ uint16_t f2bf(float f) {
    uint32_t u = __builtin_bit_cast(uint32_t, f);
    uint32_t r = (u + 0x7FFFu + ((u >> 16) & 1u)) >> 16;
    return (uint16_t)r;
}

__device__ __forceinline__ bf16x8 vfrag(ushort4 a, ushort4 b) {
    union { bf16x8 v; ushort4 u[2]; } r;
    r.u[0] = a; r.u[1] = b;
    return r.v;
}

// ---------------- prep kernels ----------------

__global__ void prep_x(const float* __restrict__ in, uint16_t* __restrict__ out) {
    int i = blockIdx.x * 256 + threadIdx.x;   // over n/4 = 786432
    float4 v = ((const float4*)in)[i];
    ushort4 o;
    o.x = f2bf(v.x); o.y = f2bf(v.y); o.z = f2bf(v.z); o.w = f2bf(v.w);
    ((ushort4*)out)[i] = o;
}

// W_effT[n][k] = w_attn[k][n] + 16 * sum_r lora_A[(c*8+r)*768+k] * lora_B[n*8+r]
__global__ void prep_weff(const float* __restrict__ w_attn,
                          const float* __restrict__ lora_A,
                          const float* __restrict__ lora_B,
                          uint16_t* __restrict__ weffT) {
    int i = blockIdx.x * 256 + threadIdx.x;   // over 2304*768
    int n = i / NXC, k = i - n * NXC;
    int c = n / NXC;
    float acc = w_attn[(size_t)k * NQKV + n];
    float d = 0.f;
#pragma unroll
    for (int r = 0; r < 8; ++r)
        d += lora_A[(size_t)(c * 8 + r) * NXC + k] * lora_B[(size_t)n * 8 + r];
    weffT[(size_t)n * NXC + k] = f2bf(acc + 16.0f * d);
}

__global__ void prep_wproj(const float* __restrict__ w_proj, uint16_t* __restrict__ wpT) {
    int i = blockIdx.x * 256 + threadIdx.x;   // over 768*768
    int n = i / NXC, k = i - n * NXC;
    wpT[(size_t)n * NXC + k] = f2bf(w_proj[(size_t)k * NXC + n]);
}

// ---------------- GEMM: C = A[M,768] * BT[N,768]^T ----------------
// MODE 0: qkv epilogue (scatter to q/k/v + present), MODE 1: plain + bias to outf

template<int MODE>
__global__ __launch_bounds__(256) void gemm_bt(
    const uint16_t* __restrict__ Abf, const uint16_t* __restrict__ BTbf,
    const float* __restrict__ bias, float* __restrict__ outf,
    uint16_t* __restrict__ q_bf, uint16_t* __restrict__ k_bf,
    uint16_t* __restrict__ vT_bf) {
    __shared__ uint16_t As[128][48];
    __shared__ uint16_t Bs[128][48];
    const int t = threadIdx.x;
    const int lane = t & 63;
    const int w = t >> 6;
    const int wr = (w >> 1) * 64;
    const int wc = (w & 1) * 64;
    const int rr = t >> 2;
    const int cc = (t & 3) << 3;
    const size_t arow0 = (size_t)blockIdx.y * 128;
    const size_t brow0 = (size_t)blockIdx.x * 128;
    const uint16_t* Ap = Abf + (arow0 + rr) * NXC + cc;
    const uint16_t* Bp = BTbf + (brow0 + rr) * NXC + cc;
    const int lr16 = lane & 15;
    const int lk = (lane >> 4) << 3;

    f32x4 acc[4][4];
#pragma unroll
    for (int m = 0; m < 4; ++m)
#pragma unroll
        for (int n = 0; n < 4; ++n) acc[m][n] = (f32x4){0.f, 0.f, 0.f, 0.f};

    for (int kt = 0; kt < 24; ++kt) {
        const int k0 = kt << 5;
        uint4 a0 = *(const uint4*)(Ap + k0);
        uint4 a1 = *(const uint4*)(Ap + (size_t)64 * NXC + k0);
        uint4 b0 = *(const uint4*)(Bp + k0);
        uint4 b1 = *(const uint4*)(Bp + (size_t)64 * NXC + k0);
        __syncthreads();
        *(uint4*)&As[rr][cc] = a0;
        *(uint4*)&As[rr + 64][cc] = a1;
        *(uint4*)&Bs[rr][cc] = b0;
        *(uint4*)&Bs[rr + 64][cc] = b1;
        __syncthreads();
        bf16x8 af[4], bv[4];
#pragma unroll
        for (int m = 0; m < 4; ++m) af[m] = *(const bf16x8*)&As[wr + m * 16 + lr16][lk];
#pragma unroll
        for (int n = 0; n < 4; ++n) bv[n] = *(const bf16x8*)&Bs[wc + n * 16 + lr16][lk];
#pragma unroll
        for (int m = 0; m < 4; ++m)
#pragma unroll
            for (int n = 0; n < 4; ++n)
                acc[m][n] = __builtin_amdgcn_mfma_f32_16x16x32_bf16(af[m], bv[n], acc[m][n], 0, 0, 0);
    }

    const int rowb = (lane >> 4) << 2;
#pragma unroll
    for (int m = 0; m < 4; ++m) {
        int grow0 = (int)arow0 + wr + m * 16 + rowb;
#pragma unroll
        for (int n = 0; n < 4; ++n) {
            int gcol = (int)brow0 + wc + n * 16 + lr16;
            float bvs = bias[gcol];
            if (MODE == 1) {
#pragma unroll
                for (int ri = 0; ri < 4; ++ri) {
                    int grow = grow0 + ri;
                    outf[(size_t)grow * NXC + gcol] = acc[m][n][ri] + bvs;
                }
            } else {
                int c = gcol >= 2 * NXC ? 2 : (gcol >= NXC ? 1 : 0);
                int e = gcol - c * NXC;
                int h = e >> 6, d = e & 63;
#pragma unroll
                for (int ri = 0; ri < 4; ++ri) {
                    int grow = grow0 + ri;
                    int b = grow >> 11, s = grow & 2047;
                    float v = acc[m][n][ri] + bvs;
                    size_t hidx = ((size_t)(b * NHEAD + h) * SS + s);
                    if (c == 0) {
                        q_bf[hidx * 64 + d] = f2bf(v * 0.125f);   // fold 1/sqrt(dh)
                    } else if (c == 1) {
                        k_bf[hidx * 64 + d] = f2bf(v);
                        outf[hidx * 64 + d] = v;
                    } else {
                        vT_bf[((size_t)(b * NHEAD + h) * 64 + d) * SS + s] = f2bf(v);
                        outf[PRESENT_HALF + hidx * 64 + d] = v;
                    }
                }
            }
        }
    }
}

// ---------------- flash attention, swapped-QK^T, lane-owns-one-q-row ----------------
// grid (32, 24); block 128 (2 waves). Wave w: q-group qi = w ? 63-bx' : bx' (mirror
// pairing -> uniform work per block). Each lane owns q = qbase + (lane&31).
// S^T = mfma_32x32x16(A=K, B=Q): lane holds 16 key-scores for its q-row.
// PV uses the SAME key permutation on V-frag (from vT) so P needs no cross-lane moves.

__global__ __launch_bounds__(128) void attn_kernel(
    const uint16_t* __restrict__ qb, const uint16_t* __restrict__ kb,
    const uint16_t* __restrict__ vtb, uint16_t* __restrict__ ab) {
    const int t = threadIdx.x;
    const int w = t >> 6, lane = t & 63;
    const int l31 = lane & 31, hi = lane >> 5;
    const int L = blockIdx.x + 32 * blockIdx.y;
    const int bh = L % 24;            // 3 heads per XCD -> K/V L2-resident
    const int qp = L / 24;            // 0..31
    const int qi = w ? (63 - qp) : qp;
    const int qbase = qi * 32;
    const uint16_t* qh = qb + (size_t)bh * (SS * 64);
    const uint16_t* kh = kb + (size_t)bh * (SS * 64);
    const uint16_t* vh = vtb + (size_t)bh * (64 * SS);
    const int q = qbase + l31;
    const float L2E = 1.44269504f;

    bf16x8 qf[4];
#pragma unroll
    for (int ks = 0; ks < 4; ++ks)
        qf[ks] = *(const bf16x8*)(qh + (size_t)q * 64 + ks * 16 + hi * 8);

    f32x16 o0, o1;
#pragma unroll
    for (int i = 0; i < 16; ++i) { o0[i] = 0.f; o1[i] = 0.f; }
    float m_run = -1e30f, l_run = 0.f;
    const int nkt = (qbase + 95) >> 6;   // 64-key tiles

    bf16x8 cka[4], ckb[4];
    {
        const uint16_t* p0 = kh + (size_t)l31 * 64 + hi * 8;
#pragma unroll
        for (int ks = 0; ks < 4; ++ks) {
            cka[ks] = *(const bf16x8*)(p0 + ks * 16);
            ckb[ks] = *(const bf16x8*)(p0 + 32 * 64 + ks * 16);
        }
    }

    for (int kt = 0; kt < nkt; ++kt) {
        const int kbase = kt << 6;
        // V loads for current tile (consumed after softmax -> latency hidden)
        // index: [sub*8 + dblk*4 + khalf*2 + part]
        ushort4 cv[16];
#pragma unroll
        for (int dblk = 0; dblk < 2; ++dblk) {
            const uint16_t* p0 = vh + (size_t)(dblk * 32 + l31) * SS + kbase + hi * 4;
#pragma unroll
            for (int sub = 0; sub < 2; ++sub)
#pragma unroll
                for (int kh2 = 0; kh2 < 2; ++kh2) {
                    cv[sub * 8 + dblk * 4 + kh2 * 2 + 0] = *(const ushort4*)(p0 + sub * 32 + kh2 * 16);
                    cv[sub * 8 + dblk * 4 + kh2 * 2 + 1] = *(const ushort4*)(p0 + sub * 32 + kh2 * 16 + 8);
                }
        }
        // prefetch next K tile
        const int nb = (kt + 1 < nkt) ? (kbase + 64) : kbase;
        bf16x8 nka[4], nkb[4];
        {
            const uint16_t* p0 = kh + (size_t)(nb + l31) * 64 + hi * 8;
#pragma unroll
            for (int ks = 0; ks < 4; ++ks) {
                nka[ks] = *(const bf16x8*)(p0 + ks * 16);
                nkb[ks] = *(const bf16x8*)(p0 + 32 * 64 + ks * 16);
            }
        }
        const bool doB = (kbase + 32) <= (qbase + 31);

        f32x16 sa, sb;
#pragma unroll
        for (int i = 0; i < 16; ++i) { sa[i] = 0.f; sb[i] = 0.f; }
#pragma unroll
        for (int ks = 0; ks < 4; ++ks)
            sa = __builtin_amdgcn_mfma_f32_32x32x16_bf16(cka[ks], qf[ks], sa, 0, 0, 0);
        if (doB) {
#pragma unroll
            for (int ks = 0; ks < 4; ++ks)
                sb = __builtin_amdgcn_mfma_f32_32x32x16_bf16(ckb[ks], qf[ks], sb, 0, 0, 0);
        }
        // causal mask (scores pre-scaled via q_bf). lane's key for reg r:
        // crow(r,hi) = (r&3) + 8*(r>>2) + 4*hi
        const int qrel = q - kbase;
        if (kbase + 31 > qbase) {
#pragma unroll
            for (int r = 0; r < 16; ++r) {
                int key = (r & 3) + 8 * (r >> 2) + 4 * hi;
                sa[r] = (key > qrel) ? -1e30f : sa[r];
            }
        }
        if (doB && (kbase + 63 > qbase)) {
#pragma unroll
            for (int r = 0; r < 16; ++r) {
                int key = 32 + (r & 3) + 8 * (r >> 2) + 4 * hi;
                sb[r] = (key > qrel) ? -1e30f : sb[r];
            }
        }
        // row max: in-lane tree + one cross-half exchange
        float tm = fmaxf(sa[0], sa[1]);
#pragma unroll
        for (int r = 2; r < 16; ++r) tm = fmaxf(tm, sa[r]);
        if (doB) {
#pragma unroll
            for (int r = 0; r < 16; ++r) tm = fmaxf(tm, sb[r]);
        }
        tm = fmaxf(tm, __shfl_xor(tm, 32));
        // defer-max (T13): only rescale when max grew by > 8
        if (__any(tm > m_run + 8.f)) {
            float nm = fmaxf(m_run, tm);
            float corr = __builtin_amdgcn_exp2f((m_run - nm) * L2E);
            l_run *= corr;
#pragma unroll
            for (int i = 0; i < 16; ++i) { o0[i] *= corr; o1[i] *= corr; }
            m_run = nm;
        }
        float ps = 0.f;
        bf16x8 pa0, pa1, pb0, pb1;
#pragma unroll
        for (int r = 0; r < 8; ++r) {
            float e0 = __builtin_amdgcn_exp2f((sa[r] - m_run) * L2E);
            float e1 = __builtin_amdgcn_exp2f((sa[8 + r] - m_run) * L2E);
            ps += e0 + e1;
            pa0[r] = (__bf16)e0;
            pa1[r] = (__bf16)e1;
        }
        if (doB) {
#pragma unroll
            for (int r = 0; r < 8; ++r) {
                float e0 = __builtin_amdgcn_exp2f((sb[r] - m_run) * L2E);
                float e1 = __builtin_amdgcn_exp2f((sb[8 + r] - m_run) * L2E);
                ps += e0 + e1;
                pb0[r] = (__bf16)e0;
                pb1[r] = (__bf16)e1;
            }
        }
        ps += __shfl_xor(ps, 32);
        l_run += ps;
        // PV: O^T[d][q] += V^T-frag x P-frag (same key permutation both sides)
        o0 = __builtin_amdgcn_mfma_f32_32x32x16_bf16(vfrag(cv[0], cv[1]), pa0, o0, 0, 0, 0);
        o0 = __builtin_amdgcn_mfma_f32_32x32x16_bf16(vfrag(cv[2], cv[3]), pa1, o0, 0, 0, 0);
        o1 = __builtin_amdgcn_mfma_f32_32x32x16_bf16(vfrag(cv[4], cv[5]), pa0, o1, 0, 0, 0);
        o1 = __builtin_amdgcn_mfma_f32_32x32x16_bf16(vfrag(cv[6], cv[7]), pa1, o1, 0, 0, 0);
        if (doB) {
            o0 = __builtin_amdgcn_mfma_f32_32x32x16_bf16(vfrag(cv[8], cv[9]), pb0, o0, 0, 0, 0);
            o0 = __builtin_amdgcn_mfma_f32_32x32x16_bf16(vfrag(cv[10], cv[11]), pb1, o0, 0, 0, 0);
            o1 = __builtin_amdgcn_mfma_f32_32x32x16_bf16(vfrag(cv[12], cv[13]), pb0, o1, 0, 0, 0);
            o1 = __builtin_amdgcn_mfma_f32_32x32x16_bf16(vfrag(cv[14], cv[15]), pb1, o1, 0, 0, 0);
        }
#pragma unroll
        for (int ks = 0; ks < 4; ++ks) { cka[ks] = nka[ks]; ckb[ks] = nkb[ks]; }
    }

    const float inv = 1.f / l_run;
    const int b = bh / NHEAD, h = bh - b * NHEAD;
    uint16_t* abp = ab + ((size_t)(b * SS + q)) * NXC + h * 64;
#pragma unroll
    for (int dblk = 0; dblk < 2; ++dblk)
#pragma unroll
        for (int rg = 0; rg < 4; ++rg) {
            f32x16 oo = dblk ? o1 : o0;
            ushort4 wv;
            wv.x = f2bf(oo[rg * 4 + 0] * inv);
            wv.y = f2bf(oo[rg * 4 + 1] * inv);
            wv.z = f2bf(oo[rg * 4 + 2] * inv);
            wv.w = f2bf(oo[rg * 4 + 3] * inv);
            *(ushort4*)(abp + dblk * 32 + rg * 8 + hi * 4) = wv;
        }
}

// ---------------- launch ----------------

extern "C" void kernel_launch(void* const* d_in, const int* in_sizes, int n_in,
                              void* d_out, int out_size, void* d_ws, size_t ws_size,
                              hipStream_t stream) {
    const float* x      = (const float*)d_in[0];
    const float* w_attn = (const float*)d_in[1];
    const float* b_attn = (const float*)d_in[2];
    const float* lora_A = (const float*)d_in[3];
    const float* lora_B = (const float*)d_in[4];
    const float* w_proj = (const float*)d_in[5];
    const float* b_proj = (const float*)d_in[6];
    float* out = (float*)d_out;
    float* present = out + (size_t)MTOT * NXC;   // 3145728

    uint16_t* ws    = (uint16_t*)d_ws;
    uint16_t* x_bf  = ws;                         // 3145728
    uint16_t* weffT = x_bf + 3145728;             // 1769472
    uint16_t* wpT   = weffT + 1769472;            // 589824
    uint16_t* q_bf  = wpT + 589824;               // 3145728
    uint16_t* k_bf  = q_bf + 3145728;             // 3145728
    uint16_t* vT_bf = k_bf + 3145728;             // 3145728
    uint16_t* a_bf  = vT_bf + 3145728;            // 3145728

    prep_x<<<dim3(3072), dim3(256), 0, stream>>>(x, x_bf);
    prep_weff<<<dim3(6912), dim3(256), 0, stream>>>(w_attn, lora_A, lora_B, weffT);
    prep_wproj<<<dim3(2304), dim3(256), 0, stream>>>(w_proj, wpT);

    gemm_bt<0><<<dim3(18, 32), dim3(256), 0, stream>>>(x_bf, weffT, b_attn, present,
                                                       q_bf, k_bf, vT_bf);
    attn_kernel<<<dim3(32, 24), dim3(128), 0, stream>>>(q_bf, k_bf, vT_bf, a_bf);
    gemm_bt<1><<<dim3(6, 32), dim3(256), 0, stream>>>(a_bf, wpT, b_proj, out,
                                                      nullptr, nullptr, nullptr);
}